// Round 3
// baseline (11958.139 us; speedup 1.0000x reference)
//
#include <hip/hip_runtime.h>
#include <hip/hip_bf16.h>
#include <hip/hip_cooperative_groups.h>

namespace cg = cooperative_groups;

// (B,C,H,G) = (4,128,8,64); F=4096, DH=16, 127 rings.
#define Bn 4
#define Cn 128
#define Hn 8
#define Fn 4096
#define NRINGS 127
#define RW 64
#define NSP 8          // key slices per (b,h)
#define SKEY 512       // keys per slice
#define KPAD 20        // LDS row stride (floats); 80B -> period-8 bank rotation, f4-aligned

// workspace offsets (floats)
#define OFF_KT  2097152
#define OFF_VT  4194304
#define OFF_PM  6291456
#define OFF_PL  6324224
#define OFF_PO  6356992
#define OFF_VA  6881280
#define OFF_KN  6881792

// ---------------------------------------------------------------------------
// init: Q0T/Kt/Vt = (Wq0/Wk0/Wv0) @ x, transposed layout [b][h][col][16]
// wg = b*64 + 64-col tile. xs = scratch LDS (>= 8192 floats).
// ---------------------------------------------------------------------------
__device__ __forceinline__ void dev_init(
    int wg, int t, const float* __restrict__ x,
    const float* __restrict__ Wq0, const float* __restrict__ Wk0,
    const float* __restrict__ Wv0,
    float* __restrict__ Q0T, float* __restrict__ Kt, float* __restrict__ Vt,
    float* xs)
{
    const int b  = wg >> 6;
    const int n0 = (wg & 63) << 6;
    for (int idx = t; idx < Cn * 64; idx += 512) {
        int c = idx >> 6, j = idx & 63;
        xs[idx] = x[(((b << 7) + c) << 12) + n0 + j];
    }
    __syncthreads();
    const int o  = t & 127;        // output channel
    const int j0 = (t >> 7) << 4;  // 16-col strip
    float aq[16], ak[16], av[16];
#pragma unroll
    for (int k = 0; k < 16; ++k) { aq[k] = 0.f; ak[k] = 0.f; av[k] = 0.f; }
    for (int c = 0; c < Cn; ++c) {
        float wq = Wq0[(o << 7) + c];
        float wk = Wk0[(o << 7) + c];
        float wv = Wv0[(o << 7) + c];
        const float* xr = &xs[(c << 6) + j0];
#pragma unroll
        for (int k = 0; k < 16; ++k) {
            float xv = xr[k];
            aq[k] += wq * xv; ak[k] += wk * xv; av[k] += wv * xv;
        }
    }
    const int h = o >> 4, d = o & 15;
#pragma unroll
    for (int k = 0; k < 16; ++k) {
        int col = n0 + j0 + k;
        int gi = (((((b << 3) + h) << 12) + col) << 4) + d;
        Q0T[gi] = aq[k]; Kt[gi] = ak[k]; Vt[gi] = av[k];
    }
    __syncthreads();   // xs (aliased LDS) reuse safety
}

// ---------------------------------------------------------------------------
// stage the WG's K/V slice (512 keys x 16d) global -> LDS
// ---------------------------------------------------------------------------
__device__ __forceinline__ void dev_stage(
    int b, int h, int sp, int t,
    const float* __restrict__ Kt, const float* __restrict__ Vt,
    float* Ks, float* Vs)
{
    const int gbase = ((((b << 3) + h) << 12) + sp * SKEY) << 4;
    for (int idx = t; idx < SKEY * 16; idx += 512) {
        int key = idx >> 4, d = idx & 15;
        Ks[key * KPAD + d] = Kt[gbase + idx];
        Vs[key * KPAD + d] = Vt[gbase + idx];
    }
    __syncthreads();
}

// ---------------------------------------------------------------------------
// flash partials for ring r over this WG's slice. 512 thr:
// part=t&15 (16 key-parts), qgrp=(t>>4)&15 (4 queries each), sub=t>>8 (2x256 keys)
// ---------------------------------------------------------------------------
__device__ __forceinline__ void dev_flash(
    int r, int n, int buf, int b, int h, int sp, int t,
    const float* __restrict__ Q0T, const int* __restrict__ rings,
    const float* Ks, const float* Vs, float* qs, int* cols, float* red,
    float* __restrict__ pm, float* __restrict__ pl, float* __restrict__ po)
{
    if (t < RW) cols[t] = (t < n) ? rings[r * RW + t] : -1;
    __syncthreads();
    for (int idx = t; idx < RW * 16; idx += 512) {
        int q = idx >> 4, d = idx & 15;
        int cq = cols[q];
        qs[q * KPAD + d] = (cq >= 0)
            ? Q0T[(((((b << 3) + h) << 12) + cq) << 4) + d] : 0.f;
    }
    __syncthreads();

    const int part = t & 15;
    const int qgrp = (t >> 4) & 15;
    const int sub  = t >> 8;
    const int w3   = (t >> 6) & 3;

    if (16 * w3 < n) {   // wave-uniform activity
        float qv[4][16], ov[4][16], mm[4], ll[4];
#pragma unroll
        for (int j = 0; j < 4; ++j) {
            const float* qr = &qs[((qgrp << 2) + j) * KPAD];
#pragma unroll
            for (int d4 = 0; d4 < 4; ++d4) {
                float4 f = *(const float4*)&qr[d4 << 2];
                qv[j][(d4<<2)+0] = f.x; qv[j][(d4<<2)+1] = f.y;
                qv[j][(d4<<2)+2] = f.z; qv[j][(d4<<2)+3] = f.w;
            }
            mm[j] = -1e30f; ll[j] = 0.f;
#pragma unroll
            for (int d = 0; d < 16; ++d) ov[j][d] = 0.f;
        }

#pragma unroll 4
        for (int i = 0; i < 16; ++i) {
            int kk = (sub << 8) + (i << 4) + part;
            const float4 k0 = *(const float4*)&Ks[kk * KPAD +  0];
            const float4 k1 = *(const float4*)&Ks[kk * KPAD +  4];
            const float4 k2 = *(const float4*)&Ks[kk * KPAD +  8];
            const float4 k3 = *(const float4*)&Ks[kk * KPAD + 12];
            float sc[4];
#pragma unroll
            for (int j = 0; j < 4; ++j) {
                sc[j] = 0.25f * (
                    qv[j][0]*k0.x + qv[j][1]*k0.y + qv[j][2]*k0.z + qv[j][3]*k0.w +
                    qv[j][4]*k1.x + qv[j][5]*k1.y + qv[j][6]*k1.z + qv[j][7]*k1.w +
                    qv[j][8]*k2.x + qv[j][9]*k2.y + qv[j][10]*k2.z + qv[j][11]*k2.w +
                    qv[j][12]*k3.x + qv[j][13]*k3.y + qv[j][14]*k3.z + qv[j][15]*k3.w);
            }
            const float4 v0 = *(const float4*)&Vs[kk * KPAD +  0];
            const float4 v1 = *(const float4*)&Vs[kk * KPAD +  4];
            const float4 v2 = *(const float4*)&Vs[kk * KPAD +  8];
            const float4 v3 = *(const float4*)&Vs[kk * KPAD + 12];
#pragma unroll
            for (int j = 0; j < 4; ++j) {
                float mn = fmaxf(mm[j], sc[j]);
                float cr = __expf(mm[j] - mn);
                float p  = __expf(sc[j] - mn);
                mm[j] = mn; ll[j] = ll[j] * cr + p;
                ov[j][0]  = ov[j][0]*cr  + p*v0.x; ov[j][1]  = ov[j][1]*cr  + p*v0.y;
                ov[j][2]  = ov[j][2]*cr  + p*v0.z; ov[j][3]  = ov[j][3]*cr  + p*v0.w;
                ov[j][4]  = ov[j][4]*cr  + p*v1.x; ov[j][5]  = ov[j][5]*cr  + p*v1.y;
                ov[j][6]  = ov[j][6]*cr  + p*v1.z; ov[j][7]  = ov[j][7]*cr  + p*v1.w;
                ov[j][8]  = ov[j][8]*cr  + p*v2.x; ov[j][9]  = ov[j][9]*cr  + p*v2.y;
                ov[j][10] = ov[j][10]*cr + p*v2.z; ov[j][11] = ov[j][11]*cr + p*v2.w;
                ov[j][12] = ov[j][12]*cr + p*v3.x; ov[j][13] = ov[j][13]*cr + p*v3.y;
                ov[j][14] = ov[j][14]*cr + p*v3.z; ov[j][15] = ov[j][15]*cr + p*v3.w;
            }
        }

        // merge the 16 key-parts (within 16-lane groups)
#pragma unroll
        for (int mask = 1; mask < 16; mask <<= 1) {
#pragma unroll
            for (int j = 0; j < 4; ++j) {
                float mo = __shfl_xor(mm[j], mask);
                float lo = __shfl_xor(ll[j], mask);
                float mn = fmaxf(mm[j], mo);
                float c0 = __expf(mm[j] - mn), c1 = __expf(mo - mn);
                ll[j] = ll[j] * c0 + lo * c1;
#pragma unroll
                for (int d = 0; d < 16; ++d)
                    ov[j][d] = ov[j][d] * c0 + __shfl_xor(ov[j][d], mask) * c1;
                mm[j] = mn;
            }
        }
        if (part == 0) {
#pragma unroll
            for (int j = 0; j < 4; ++j) {
                float* rr = &red[((sub << 6) + (qgrp << 2) + j) * 18];
#pragma unroll
                for (int d = 0; d < 16; ++d) rr[d] = ov[j][d];
                rr[16] = mm[j]; rr[17] = ll[j];
            }
        }
    }
    __syncthreads();
    if (t < n) {           // n <= 64
        const float* r0 = &red[t * 18];
        const float* r1 = &red[(64 + t) * 18];
        float m0 = r0[16], m1 = r1[16];
        float M = fmaxf(m0, m1);
        float c0 = __expf(m0 - M), c1 = __expf(m1 - M);
        int pidx = ((((buf << 5) + (b << 3) + h) << 3) + sp) * 64 + t;
        pm[pidx] = M;
        pl[pidx] = r0[17] * c0 + r1[17] * c1;
        float* pp = &po[pidx << 4];
#pragma unroll
        for (int d = 0; d < 16; ++d) pp[d] = r0[d] * c0 + r1[d] * c1;
    }
}

// ---------------------------------------------------------------------------
// combine ring r's partials for the cols owned by this WG's slice; write feats
// (h==0 WGs) and this h's updated K/V rows (to LDS and/or global).
// ---------------------------------------------------------------------------
template<bool WLDS, bool WGLB>
__device__ __forceinline__ void dev_combine(
    int r, int n, int buf, int b, int h, int sp, int t,
    const float* __restrict__ x, const float* __restrict__ Wk0,
    const float* __restrict__ Wv0, const int* __restrict__ rings,
    const float* __restrict__ pm, const float* __restrict__ pl,
    const float* __restrict__ po, float* __restrict__ feats,
    float* Ks, float* Vs, float* __restrict__ Kt, float* __restrict__ Vt,
    int* cols, int* ownIdx, int* ownCnt, float* outc)
{
    if (t < RW) cols[t] = (t < n) ? rings[r * RW + t] : -1;
    if (t == 0) *ownCnt = 0;
    __syncthreads();
    if (t < n) {
        int cq = cols[t];
        if (cq >= sp * SKEY && cq < sp * SKEY + SKEY) {
            int slot = atomicAdd(ownCnt, 1);
            ownIdx[slot] = t;
        }
    }
    __syncthreads();
    const int cnt = *ownCnt;
    for (int base = 0; base < cnt; base += 4) {
        {
            int slot = t >> 7;          // 0..3
            int c = t & 127;
            int ow = base + slot;
            if (ow < cnt) {
                int j = ownIdx[ow];
                int col = cols[j];
                int hh = c >> 4, dd = c & 15;
                int p0 = ((((buf << 5) + (b << 3) + hh) << 3) << 6) + j;
                float mstar = -1e30f;
#pragma unroll
                for (int s2 = 0; s2 < NSP; ++s2)
                    mstar = fmaxf(mstar, pm[p0 + (s2 << 6)]);
                float lstar = 0.f, osum = 0.f;
#pragma unroll
                for (int s2 = 0; s2 < NSP; ++s2) {
                    int pi = p0 + (s2 << 6);
                    float e = __expf(pm[pi] - mstar);
                    lstar += pl[pi] * e;
                    osum  += po[(pi << 4) + dd] * e;
                }
                float outv = osum / lstar + x[(((b << 7) + c) << 12) + col];
                outc[(slot << 7) + c] = outv;
                if (h == 0) feats[(((b << 7) + c) << 12) + col] = outv;
            }
        }
        __syncthreads();
        if (t < 128) {
            int slot = t >> 5;          // 0..3
            int ow = base + slot;
            if (ow < cnt) {
                int task = t & 31;
                int isV = task >> 4, dd = task & 15;
                int j = ownIdx[ow];
                int col = cols[j];
                int row = (h << 4) + dd;
                const float* W = isV ? Wv0 : Wk0;
                const float* oc = &outc[slot << 7];
                float acc = 0.f;
                for (int c2 = 0; c2 < Cn; ++c2)
                    acc += W[(row << 7) + c2] * oc[c2];
                if (WLDS) {
                    float* dst = isV ? Vs : Ks;
                    dst[(col - sp * SKEY) * KPAD + dd] = acc;
                }
                if (WGLB) {
                    float* dst = isV ? Vt : Kt;
                    dst[(((((b << 3) + h) << 12) + col) << 4) + dd] = acc;
                }
            }
        }
        __syncthreads();
    }
}

// ---------------------------------------------------------------------------
// Persistent cooperative kernel: 256 WGs x 512 thr, 1 WG/CU. One grid.sync
// per ring (partials double-buffered by ring parity; K/V updates are WG-local).
// ---------------------------------------------------------------------------
__global__ __launch_bounds__(512, 2) void ringLoop(
    const float* __restrict__ x, const float* __restrict__ Wq0,
    const float* __restrict__ Wk0, const float* __restrict__ Wv0,
    const int* __restrict__ rings, const int* __restrict__ rsz,
    float* __restrict__ Q0T, float* __restrict__ Kt, float* __restrict__ Vt,
    float* __restrict__ pm, float* __restrict__ pl, float* __restrict__ po,
    float* __restrict__ feats)
{
    __shared__ float Ks[SKEY * KPAD];
    __shared__ float Vs[SKEY * KPAD];
    __shared__ float qs[RW * KPAD];
    __shared__ float red[2 * 64 * 18];
    __shared__ float outc[4 * 128];
    __shared__ int   cols[RW];
    __shared__ int   ownIdx[16];
    __shared__ int   ownCnt;

    cg::grid_group grid = cg::this_grid();
    const int wg = blockIdx.x, t = threadIdx.x;

    dev_init(wg, t, x, Wq0, Wk0, Wv0, Q0T, Kt, Vt, Ks);
    __threadfence();
    grid.sync();

    const int b = wg >> 6, h = (wg >> 3) & 7, sp = wg & 7;
    dev_stage(b, h, sp, t, Kt, Vt, Ks, Vs);

    for (int r = 0; r < NRINGS; ++r) {
        const int n = rsz[r];
        dev_flash(r, n, r & 1, b, h, sp, t, Q0T, rings, Ks, Vs, qs, cols, red,
                  pm, pl, po);
        __threadfence();
        grid.sync();
        dev_combine<true, false>(r, n, r & 1, b, h, sp, t, x, Wk0, Wv0, rings,
                                 pm, pl, po, feats, Ks, Vs, nullptr, nullptr,
                                 cols, ownIdx, &ownCnt, outc);
    }
}

// ---------------------------------------------------------------------------
// Fallback (non-persistent) path — used only if the co-op launch errors.
// ---------------------------------------------------------------------------
__global__ __launch_bounds__(512, 2) void fbInit(
    const float* __restrict__ x, const float* __restrict__ Wq0,
    const float* __restrict__ Wk0, const float* __restrict__ Wv0,
    float* __restrict__ Q0T, float* __restrict__ Kt, float* __restrict__ Vt)
{
    __shared__ float xs[Cn * 64];
    dev_init(blockIdx.x, threadIdx.x, x, Wq0, Wk0, Wv0, Q0T, Kt, Vt, xs);
}

__global__ __launch_bounds__(512, 2) void fbFlash(
    const float* __restrict__ Q0T, const float* __restrict__ Kt,
    const float* __restrict__ Vt, const int* __restrict__ rings,
    const int* __restrict__ rsz, float* __restrict__ pm,
    float* __restrict__ pl, float* __restrict__ po, int r)
{
    __shared__ float Ks[SKEY * KPAD];
    __shared__ float Vs[SKEY * KPAD];
    __shared__ float qs[RW * KPAD];
    __shared__ float red[2 * 64 * 18];
    __shared__ int   cols[RW];
    const int wg = blockIdx.x, t = threadIdx.x;
    const int b = wg >> 6, h = (wg >> 3) & 7, sp = wg & 7;
    const int n = rsz[r];
    dev_stage(b, h, sp, t, Kt, Vt, Ks, Vs);
    dev_flash(r, n, 0, b, h, sp, t, Q0T, rings, Ks, Vs, qs, cols, red,
              pm, pl, po);
}

__global__ __launch_bounds__(512, 2) void fbCombine(
    const float* __restrict__ x, const float* __restrict__ Wk0,
    const float* __restrict__ Wv0, const int* __restrict__ rings,
    const int* __restrict__ rsz, const float* __restrict__ pm,
    const float* __restrict__ pl, const float* __restrict__ po,
    float* __restrict__ feats, float* __restrict__ Kt, float* __restrict__ Vt,
    int r)
{
    __shared__ float outc[4 * 128];
    __shared__ int   cols[RW];
    __shared__ int   ownIdx[16];
    __shared__ int   ownCnt;
    const int wg = blockIdx.x, t = threadIdx.x;
    const int b = wg >> 6, h = (wg >> 3) & 7, sp = wg & 7;
    const int n = rsz[r];
    dev_combine<false, true>(r, n, 0, b, h, sp, t, x, Wk0, Wv0, rings,
                             pm, pl, po, feats, nullptr, nullptr, Kt, Vt,
                             cols, ownIdx, &ownCnt, outc);
}

// ---------------------------------------------------------------------------
// Epilogues (unchanged from the passing R1 version)
// ---------------------------------------------------------------------------
__global__ __launch_bounds__(128) void epi1(
    const float* __restrict__ feats, const float* __restrict__ Wv0,
    const float* __restrict__ Wk1, const int* __restrict__ rings,
    float* __restrict__ Va, float* __restrict__ Kn)
{
    int b = blockIdx.x;
    int i = threadIdx.x;
    int anchor = rings[0];
    __shared__ float la[128];
    __shared__ float kk2[128];
    la[i] = feats[((b * Cn + i) << 12) + anchor];
    __syncthreads();
    float va = 0.f, k1 = 0.f;
    for (int c = 0; c < 128; ++c) {
        va += Wv0[i * 128 + c] * la[c];
        k1 += Wk1[i * 128 + c] * la[c];
    }
    Va[b * 128 + i] = va;
    kk2[i] = k1 * k1;
    __syncthreads();
    float ss = 0.f;
    int hb = i & ~15;
    for (int d = 0; d < 16; ++d) ss += kk2[hb + d];
    Kn[b * 128 + i] = k1 * rsqrtf(ss + 1e-8f);
}

__global__ __launch_bounds__(128) void epi2(
    const float* __restrict__ x, const float* __restrict__ Wq1,
    const float* __restrict__ Va, const float* __restrict__ Kn,
    float* __restrict__ scores)
{
    int col = blockIdx.x & (Fn - 1);
    int b   = blockIdx.x >> 12;
    int i = threadIdx.x;
    __shared__ float lx[128];
    __shared__ float q2[128];
    __shared__ float mp[128];
    lx[i] = x[((b * Cn + i) << 12) + col] + Va[b * 128 + i];
    __syncthreads();
    float q1 = 0.f;
    for (int c = 0; c < 128; ++c) q1 += Wq1[i * 128 + c] * lx[c];
    q2[i] = q1 * q1;
    __syncthreads();
    float ss = 0.f;
    int hb = i & ~15;
    for (int d = 0; d < 16; ++d) ss += q2[hb + d];
    float qn = q1 * rsqrtf(ss + 1e-8f);
    mp[i] = qn * Kn[b * 128 + i];
    __syncthreads();
    for (int st = 64; st > 0; st >>= 1) {
        if (i < st) mp[i] += mp[i + st];
        __syncthreads();
    }
    if (i == 0) scores[(b << 12) + col] = 0.5f + mp[0] * (1.0f / 16.0f);
}

// ---------------------------------------------------------------------------
// Launcher
// ---------------------------------------------------------------------------
extern "C" void kernel_launch(void* const* d_in, const int* in_sizes, int n_in,
                              void* d_out, int out_size, void* d_ws, size_t ws_size,
                              hipStream_t stream) {
    const float* x   = (const float*)d_in[0];
    const float* Wq0 = (const float*)d_in[1];
    const float* Wk0 = (const float*)d_in[2];
    const float* Wv0 = (const float*)d_in[3];
    const float* Wq1 = (const float*)d_in[4];
    const float* Wk1 = (const float*)d_in[5];
    const int*   rings = (const int*)d_in[6];
    const int*   rsz   = (const int*)d_in[7];

    float* feats  = (float*)d_out;                 // (B,C,F)
    float* scores = feats + Bn * Cn * Fn;          // (B,F)

    float* ws  = (float*)d_ws;
    float* Q0T = ws;
    float* Kt  = ws + OFF_KT;
    float* Vt  = ws + OFF_VT;
    float* pm  = ws + OFF_PM;
    float* pl  = ws + OFF_PL;
    float* po  = ws + OFF_PO;
    float* Va  = ws + OFF_VA;
    float* Kn  = ws + OFF_KN;

    void* args[] = { (void*)&x, (void*)&Wq0, (void*)&Wk0, (void*)&Wv0,
                     (void*)&rings, (void*)&rsz,
                     (void*)&Q0T, (void*)&Kt, (void*)&Vt,
                     (void*)&pm, (void*)&pl, (void*)&po, (void*)&feats };
    hipError_t le = hipLaunchCooperativeKernel((void*)ringLoop, dim3(256),
                                               dim3(512), args, 0, stream);
    if (le != hipSuccess) {
        // fallback: non-persistent path, identical math
        fbInit<<<256, 512, 0, stream>>>(x, Wq0, Wk0, Wv0, Q0T, Kt, Vt);
        for (int r = 0; r < NRINGS; ++r) {
            fbFlash<<<256, 512, 0, stream>>>(Q0T, Kt, Vt, rings, rsz,
                                             pm, pl, po, r);
            fbCombine<<<256, 512, 0, stream>>>(x, Wk0, Wv0, rings, rsz,
                                               pm, pl, po, feats, Kt, Vt, r);
        }
    }

    epi1<<<Bn, 128, 0, stream>>>(feats, Wv0, Wk1, rings, Va, Kn);
    epi2<<<Bn * Fn, 128, 0, stream>>>(x, Wq1, Va, Kn, scores);
}

// Round 4
// 3768.791 us; speedup vs baseline: 3.1729x; 3.1729x over previous
//
#include <hip/hip_runtime.h>
#include <hip/hip_bf16.h>

// (B,C,H,G) = (4,128,8,64); F=4096, DH=16, 127 rings.
#define Bn 4
#define Cn 128
#define Hn 8
#define Fn 4096
#define NRINGS 127
#define RW 64
#define NSP 8          // key slices per (b,h)
#define SKEY 512       // keys per slice
#define KPAD 20        // LDS row stride (floats); 80B -> period-8 bank rotation, f4-aligned

// workspace offsets (floats)
#define OFF_KT  2097152
#define OFF_VT  4194304
#define OFF_PM  6291456   // 2 x 16384
#define OFF_PL  6324224
#define OFF_PO  6356992   // 2 x 16384 x 16
#define OFF_VA  6881280
#define OFF_KN  6881792

// ---------------------------------------------------------------------------
// init: Q0T/Kt/Vt = (Wq0/Wk0/Wv0) @ x, transposed layout [b][h][col][16]
// ---------------------------------------------------------------------------
__global__ __launch_bounds__(512, 2) void initQKV(
    const float* __restrict__ x, const float* __restrict__ Wq0,
    const float* __restrict__ Wk0, const float* __restrict__ Wv0,
    float* __restrict__ Q0T, float* __restrict__ Kt, float* __restrict__ Vt)
{
    __shared__ float xs[Cn * 64];
    const int wg = blockIdx.x, t = threadIdx.x;
    const int b  = wg >> 6;
    const int n0 = (wg & 63) << 6;
    for (int idx = t; idx < Cn * 64; idx += 512) {
        int c = idx >> 6, j = idx & 63;
        xs[idx] = x[(((b << 7) + c) << 12) + n0 + j];
    }
    __syncthreads();
    const int o  = t & 127;        // output channel
    const int j0 = (t >> 7) << 4;  // 16-col strip
    float aq[16], ak[16], av[16];
#pragma unroll
    for (int k = 0; k < 16; ++k) { aq[k] = 0.f; ak[k] = 0.f; av[k] = 0.f; }
    for (int c = 0; c < Cn; ++c) {
        float wq = Wq0[(o << 7) + c];
        float wk = Wk0[(o << 7) + c];
        float wv = Wv0[(o << 7) + c];
        const float* xr = &xs[(c << 6) + j0];
#pragma unroll
        for (int k = 0; k < 16; ++k) {
            float xv = xr[k];
            aq[k] += wq * xv; ak[k] += wk * xv; av[k] += wv * xv;
        }
    }
    const int h = o >> 4, d = o & 15;
#pragma unroll
    for (int k = 0; k < 16; ++k) {
        int col = n0 + j0 + k;
        int gi = (((((b << 3) + h) << 12) + col) << 4) + d;
        Q0T[gi] = aq[k]; Kt[gi] = ak[k]; Vt[gi] = av[k];
    }
}

// ---------------------------------------------------------------------------
// Fused per-ring kernel. WG (b,h,sp) with 512 threads:
//   1) stage its (512 key x 16d) K/V slice from global into LDS
//   2) combine ring r-1 from prev launch's partials: write feats (h==0),
//      recompute its own h's K/V rows for updated cols -> LDS + global
//   3) flash partials for ring r over the (now current) LDS slice
// TAIL instantiation: combine-only (r == NRINGS).
// ---------------------------------------------------------------------------
template<bool TAIL>
__global__ __launch_bounds__(512, 2) void fusedRing(
    const float* __restrict__ x, const float* __restrict__ Wk0,
    const float* __restrict__ Wv0, const int* __restrict__ rings,
    const int* __restrict__ rsz, const float* __restrict__ Q0T,
    float* __restrict__ Kt, float* __restrict__ Vt,
    float* __restrict__ pm, float* __restrict__ pl, float* __restrict__ po,
    float* __restrict__ feats, int r)
{
    __shared__ float Ks[SKEY * KPAD];
    __shared__ float Vs[SKEY * KPAD];
    __shared__ float qs[RW * KPAD];
    __shared__ float red[2 * 64 * 18];
    __shared__ float outc[4 * 128];
    __shared__ int   cols[RW];
    __shared__ int   ownIdx[16];
    __shared__ int   ownCnt;

    const int wg = blockIdx.x, t = threadIdx.x;
    const int b = wg >> 6, h = (wg >> 3) & 7, sp = wg & 7;

    // ---------------- 1) stage K/V slice ----------------
    if (!TAIL) {
        const int gbase = ((((b << 3) + h) << 12) + sp * SKEY) << 4;
        for (int idx = t; idx < SKEY * 4; idx += 512) {
            int key = idx >> 2, p4 = (idx & 3) << 2;
            *(float4*)&Ks[key * KPAD + p4] =
                *(const float4*)&Kt[gbase + (key << 4) + p4];
            *(float4*)&Vs[key * KPAD + p4] =
                *(const float4*)&Vt[gbase + (key << 4) + p4];
        }
    }

    // ---------------- 2) combine ring r-1 ----------------
    if (r > 0) {
        const int rp   = r - 1;
        const int np   = rsz[rp];
        const int bufp = rp & 1;
        if (t < RW) cols[t] = (t < np) ? rings[rp * RW + t] : -1;
        if (t == 0) ownCnt = 0;
        __syncthreads();
        if (t < np) {
            int cq = cols[t];
            if (cq >= sp * SKEY && cq < sp * SKEY + SKEY) {
                int slot = atomicAdd(&ownCnt, 1);
                ownIdx[slot] = t;
            }
        }
        __syncthreads();
        const int cnt = ownCnt;
        for (int base = 0; base < cnt; base += 4) {
            {
                int slot = t >> 7;          // 0..3
                int c = t & 127;
                int ow = base + slot;
                if (ow < cnt) {
                    int j = ownIdx[ow];
                    int col = cols[j];
                    int hh = c >> 4, dd = c & 15;
                    int p0 = (((bufp << 5) + (b << 3) + hh) << 9) + j;
                    float mstar = -1e30f;
#pragma unroll
                    for (int s2 = 0; s2 < NSP; ++s2)
                        mstar = fmaxf(mstar, pm[p0 + (s2 << 6)]);
                    float lstar = 0.f, osum = 0.f;
#pragma unroll
                    for (int s2 = 0; s2 < NSP; ++s2) {
                        int pi = p0 + (s2 << 6);
                        float e = __expf(pm[pi] - mstar);
                        lstar += pl[pi] * e;
                        osum  += po[(pi << 4) + dd] * e;
                    }
                    float outv = osum / lstar + x[(((b << 7) + c) << 12) + col];
                    outc[(slot << 7) + c] = outv;
                    if (h == 0) feats[(((b << 7) + c) << 12) + col] = outv;
                }
            }
            __syncthreads();
            if (!TAIL && t < 128) {
                int slot = t >> 5;          // 0..3
                int ow = base + slot;
                if (ow < cnt) {
                    int task = t & 31;
                    int isV = task >> 4, dd = task & 15;
                    int j = ownIdx[ow];
                    int col = cols[j];
                    int row = (h << 4) + dd;
                    const float* W = isV ? Wv0 : Wk0;
                    const float* oc = &outc[slot << 7];
                    float acc = 0.f;
                    for (int c2 = 0; c2 < Cn; ++c2)
                        acc += W[(row << 7) + c2] * oc[c2];
                    int gi = (((((b << 3) + h) << 12) + col) << 4) + dd;
                    if (isV) { Vs[(col - sp * SKEY) * KPAD + dd] = acc; Vt[gi] = acc; }
                    else     { Ks[(col - sp * SKEY) * KPAD + dd] = acc; Kt[gi] = acc; }
                }
            }
            __syncthreads();
        }
    }
    if (TAIL) return;

    // ---------------- 3) flash ring r ----------------
    const int n   = rsz[r];
    const int buf = r & 1;
    if (t < RW) cols[t] = (t < n) ? rings[r * RW + t] : -1;
    __syncthreads();
    for (int idx = t; idx < RW * 16; idx += 512) {
        int q = idx >> 4, d = idx & 15;
        int cq = cols[q];
        qs[q * KPAD + d] = (cq >= 0)
            ? Q0T[(((((b << 3) + h) << 12) + cq) << 4) + d] : 0.f;
    }
    __syncthreads();

    const int part = t & 15;
    const int qgrp = (t >> 4) & 15;
    const int sub  = t >> 8;
    const int w3   = (t >> 6) & 3;

    if (16 * w3 < n) {   // wave-uniform activity
        float qv[4][16], ov[4][16], mm[4], ll[4];
#pragma unroll
        for (int j = 0; j < 4; ++j) {
            const float* qr = &qs[((qgrp << 2) + j) * KPAD];
#pragma unroll
            for (int d4 = 0; d4 < 4; ++d4) {
                float4 f = *(const float4*)&qr[d4 << 2];
                qv[j][(d4<<2)+0] = f.x; qv[j][(d4<<2)+1] = f.y;
                qv[j][(d4<<2)+2] = f.z; qv[j][(d4<<2)+3] = f.w;
            }
            mm[j] = -1e30f; ll[j] = 0.f;
#pragma unroll
            for (int d = 0; d < 16; ++d) ov[j][d] = 0.f;
        }

#pragma unroll 4
        for (int i = 0; i < 16; ++i) {
            int kk = (sub << 8) + (i << 4) + part;
            const float4 k0 = *(const float4*)&Ks[kk * KPAD +  0];
            const float4 k1 = *(const float4*)&Ks[kk * KPAD +  4];
            const float4 k2 = *(const float4*)&Ks[kk * KPAD +  8];
            const float4 k3 = *(const float4*)&Ks[kk * KPAD + 12];
            float sc[4];
#pragma unroll
            for (int j = 0; j < 4; ++j) {
                sc[j] = 0.25f * (
                    qv[j][0]*k0.x + qv[j][1]*k0.y + qv[j][2]*k0.z + qv[j][3]*k0.w +
                    qv[j][4]*k1.x + qv[j][5]*k1.y + qv[j][6]*k1.z + qv[j][7]*k1.w +
                    qv[j][8]*k2.x + qv[j][9]*k2.y + qv[j][10]*k2.z + qv[j][11]*k2.w +
                    qv[j][12]*k3.x + qv[j][13]*k3.y + qv[j][14]*k3.z + qv[j][15]*k3.w);
            }
            const float4 v0 = *(const float4*)&Vs[kk * KPAD +  0];
            const float4 v1 = *(const float4*)&Vs[kk * KPAD +  4];
            const float4 v2 = *(const float4*)&Vs[kk * KPAD +  8];
            const float4 v3 = *(const float4*)&Vs[kk * KPAD + 12];
#pragma unroll
            for (int j = 0; j < 4; ++j) {
                float mn = fmaxf(mm[j], sc[j]);
                float cr = __expf(mm[j] - mn);
                float p  = __expf(sc[j] - mn);
                mm[j] = mn; ll[j] = ll[j] * cr + p;
                ov[j][0]  = ov[j][0]*cr  + p*v0.x; ov[j][1]  = ov[j][1]*cr  + p*v0.y;
                ov[j][2]  = ov[j][2]*cr  + p*v0.z; ov[j][3]  = ov[j][3]*cr  + p*v0.w;
                ov[j][4]  = ov[j][4]*cr  + p*v1.x; ov[j][5]  = ov[j][5]*cr  + p*v1.y;
                ov[j][6]  = ov[j][6]*cr  + p*v1.z; ov[j][7]  = ov[j][7]*cr  + p*v1.w;
                ov[j][8]  = ov[j][8]*cr  + p*v2.x; ov[j][9]  = ov[j][9]*cr  + p*v2.y;
                ov[j][10] = ov[j][10]*cr + p*v2.z; ov[j][11] = ov[j][11]*cr + p*v2.w;
                ov[j][12] = ov[j][12]*cr + p*v3.x; ov[j][13] = ov[j][13]*cr + p*v3.y;
                ov[j][14] = ov[j][14]*cr + p*v3.z; ov[j][15] = ov[j][15]*cr + p*v3.w;
            }
        }

        // merge the 16 key-parts (within 16-lane groups)
#pragma unroll
        for (int mask = 1; mask < 16; mask <<= 1) {
#pragma unroll
            for (int j = 0; j < 4; ++j) {
                float mo = __shfl_xor(mm[j], mask);
                float lo = __shfl_xor(ll[j], mask);
                float mn = fmaxf(mm[j], mo);
                float c0 = __expf(mm[j] - mn), c1 = __expf(mo - mn);
                ll[j] = ll[j] * c0 + lo * c1;
#pragma unroll
                for (int d = 0; d < 16; ++d)
                    ov[j][d] = ov[j][d] * c0 + __shfl_xor(ov[j][d], mask) * c1;
                mm[j] = mn;
            }
        }
        if (part == 0) {
#pragma unroll
            for (int j = 0; j < 4; ++j) {
                float* rr = &red[((sub << 6) + (qgrp << 2) + j) * 18];
#pragma unroll
                for (int d = 0; d < 16; ++d) rr[d] = ov[j][d];
                rr[16] = mm[j]; rr[17] = ll[j];
            }
        }
    }
    __syncthreads();
    if (t < n) {           // n <= 64
        const float* r0 = &red[t * 18];
        const float* r1 = &red[(64 + t) * 18];
        float m0 = r0[16], m1 = r1[16];
        float M = fmaxf(m0, m1);
        float c0 = __expf(m0 - M), c1 = __expf(m1 - M);
        int pidx = (((buf << 5) + (b << 3) + h) << 9) + (sp << 6) + t;
        pm[pidx] = M;
        pl[pidx] = r0[17] * c0 + r1[17] * c1;
        float* pp = &po[pidx << 4];
#pragma unroll
        for (int d = 0; d < 16; ++d) pp[d] = r0[d] * c0 + r1[d] * c1;
    }
}

// ---------------------------------------------------------------------------
// Epilogues
// ---------------------------------------------------------------------------
__global__ __launch_bounds__(128) void epi1(
    const float* __restrict__ feats, const float* __restrict__ Wv0,
    const float* __restrict__ Wk1, const int* __restrict__ rings,
    float* __restrict__ Va, float* __restrict__ Kn)
{
    int b = blockIdx.x;
    int i = threadIdx.x;
    int anchor = rings[0];
    __shared__ float la[128];
    __shared__ float kk2[128];
    la[i] = feats[((b * Cn + i) << 12) + anchor];
    __syncthreads();
    float va = 0.f, k1 = 0.f;
    for (int c = 0; c < 128; ++c) {
        va += Wv0[i * 128 + c] * la[c];
        k1 += Wk1[i * 128 + c] * la[c];
    }
    Va[b * 128 + i] = va;
    kk2[i] = k1 * k1;
    __syncthreads();
    float ss = 0.f;
    int hb = i & ~15;
    for (int d = 0; d < 16; ++d) ss += kk2[hb + d];
    Kn[b * 128 + i] = k1 * rsqrtf(ss + 1e-8f);
}

__global__ __launch_bounds__(128) void epi2(
    const float* __restrict__ x, const float* __restrict__ Wq1,
    const float* __restrict__ Va, const float* __restrict__ Kn,
    float* __restrict__ scores)
{
    int col = blockIdx.x & (Fn - 1);
    int b   = blockIdx.x >> 12;
    int i = threadIdx.x;
    __shared__ float lx[128];
    __shared__ float q2[128];
    __shared__ float mp[128];
    lx[i] = x[((b * Cn + i) << 12) + col] + Va[b * 128 + i];
    __syncthreads();
    float q1 = 0.f;
    for (int c = 0; c < 128; ++c) q1 += Wq1[i * 128 + c] * lx[c];
    q2[i] = q1 * q1;
    __syncthreads();
    float ss = 0.f;
    int hb = i & ~15;
    for (int d = 0; d < 16; ++d) ss += q2[hb + d];
    float qn = q1 * rsqrtf(ss + 1e-8f);
    mp[i] = qn * Kn[b * 128 + i];
    __syncthreads();
    for (int st = 64; st > 0; st >>= 1) {
        if (i < st) mp[i] += mp[i + st];
        __syncthreads();
    }
    if (i == 0) scores[(b << 12) + col] = 0.5f + mp[0] * (1.0f / 16.0f);
}

// ---------------------------------------------------------------------------
// Launcher: 1 init + 127 fused + 1 tail + 2 epilogues = 131 launches.
// ---------------------------------------------------------------------------
extern "C" void kernel_launch(void* const* d_in, const int* in_sizes, int n_in,
                              void* d_out, int out_size, void* d_ws, size_t ws_size,
                              hipStream_t stream) {
    const float* x   = (const float*)d_in[0];
    const float* Wq0 = (const float*)d_in[1];
    const float* Wk0 = (const float*)d_in[2];
    const float* Wv0 = (const float*)d_in[3];
    const float* Wq1 = (const float*)d_in[4];
    const float* Wk1 = (const float*)d_in[5];
    const int*   rings = (const int*)d_in[6];
    const int*   rsz   = (const int*)d_in[7];

    float* feats  = (float*)d_out;                 // (B,C,F)
    float* scores = feats + Bn * Cn * Fn;          // (B,F)

    float* ws  = (float*)d_ws;
    float* Q0T = ws;
    float* Kt  = ws + OFF_KT;
    float* Vt  = ws + OFF_VT;
    float* pm  = ws + OFF_PM;
    float* pl  = ws + OFF_PL;
    float* po  = ws + OFF_PO;
    float* Va  = ws + OFF_VA;
    float* Kn  = ws + OFF_KN;

    initQKV<<<256, 512, 0, stream>>>(x, Wq0, Wk0, Wv0, Q0T, Kt, Vt);

    for (int r = 0; r < NRINGS; ++r) {
        fusedRing<false><<<256, 512, 0, stream>>>(
            x, Wk0, Wv0, rings, rsz, Q0T, Kt, Vt, pm, pl, po, feats, r);
    }
    fusedRing<true><<<256, 512, 0, stream>>>(
        x, Wk0, Wv0, rings, rsz, Q0T, Kt, Vt, pm, pl, po, feats, NRINGS);

    epi1<<<Bn, 128, 0, stream>>>(feats, Wv0, Wk1, rings, Va, Kn);
    epi2<<<Bn * Fn, 128, 0, stream>>>(x, Wq1, Va, Kn, scores);
}

// Round 5
// 1781.288 us; speedup vs baseline: 6.7132x; 2.1158x over previous
//
#include <hip/hip_runtime.h>
#include <hip/hip_bf16.h>

// (B,C,H,G) = (4,128,8,64); F=4096, DH=16, 127 rings.
#define Bn 4
#define Cn 128
#define Fn 4096
#define NRINGS 127

typedef short bhalf4 __attribute__((ext_vector_type(4)));
typedef float f32x4  __attribute__((ext_vector_type(4)));

// workspace offsets (float-slot units)
#define OFF_K   1048576
#define OFF_V   2097152
#define OFF_PM  3145728
#define OFF_PL  3211264
#define OFF_PO  3276800
#define OFF_VA  4325376
#define OFF_KN  4325888

__device__ __forceinline__ ushort f2bf(float f) {
    __hip_bfloat16 h = __float2bfloat16(f);
    return *reinterpret_cast<ushort*>(&h);
}

// ---------------------------------------------------------------------------
// init: Q0bf/Kbf = rows [b][h][col][16] bf16; Vbf transposed [b][h][d][col] bf16
// grid = 256 (b x 64-col tiles), 512 thr
// ---------------------------------------------------------------------------
__global__ __launch_bounds__(512, 2) void initQKV(
    const float* __restrict__ x, const float* __restrict__ Wq0,
    const float* __restrict__ Wk0, const float* __restrict__ Wv0,
    ushort* __restrict__ Q0bf, ushort* __restrict__ Kbf, ushort* __restrict__ Vbf)
{
    __shared__ float xs[Cn * 64];
    const int wg = blockIdx.x, t = threadIdx.x;
    const int b = wg >> 6, n0 = (wg & 63) << 6;
    for (int idx = t; idx < Cn * 64; idx += 512) {
        int c = idx >> 6, j = idx & 63;
        xs[idx] = x[(((b << 7) + c) << 12) + n0 + j];
    }
    __syncthreads();
    const int o = t & 127, j0 = (t >> 7) << 4;
    float aq[16], ak[16], av[16];
#pragma unroll
    for (int k = 0; k < 16; ++k) { aq[k] = 0.f; ak[k] = 0.f; av[k] = 0.f; }
    for (int c = 0; c < Cn; ++c) {
        float wq = Wq0[(o << 7) + c];
        float wk = Wk0[(o << 7) + c];
        float wv = Wv0[(o << 7) + c];
        const float* xr = &xs[(c << 6) + j0];
#pragma unroll
        for (int k = 0; k < 16; ++k) {
            float xv = xr[k];
            aq[k] += wq * xv; ak[k] += wk * xv; av[k] += wv * xv;
        }
    }
    const int h = o >> 4, d = o & 15;
    const int bh = (b << 3) + h;
#pragma unroll
    for (int k = 0; k < 16; ++k) {
        int col = n0 + j0 + k;
        int qi = ((bh << 12) + col) * 16 + d;
        Q0bf[qi] = f2bf(aq[k]);
        Kbf[qi]  = f2bf(ak[k]);
    }
    uint vv[8];
#pragma unroll
    for (int k2 = 0; k2 < 8; ++k2)
        vv[k2] = (uint)f2bf(av[2*k2]) | ((uint)f2bf(av[2*k2+1]) << 16);
    uint4* dst = (uint4*)&Vbf[(((bh << 4) + d) << 12) + n0 + j0];
    dst[0] = make_uint4(vv[0], vv[1], vv[2], vv[3]);
    dst[1] = make_uint4(vv[4], vv[5], vv[6], vv[7]);
}

// ---------------------------------------------------------------------------
// Fused per-ring kernel: WG (b,h,sp of 512 keys), 512 thr = 8 waves.
//   1) stage bf16 K rows (48B-padded) + V^T rows + ring-r Q into LDS
//   2) combine ring r-1 (16 slice-partials), write feats (h==0), recompute
//      own-h K/V rows for updated cols -> LDS patch + global bf16
//   3) MFMA flash for ring r: wave w: qtile=w&3, key-half=w>>2 (256 keys)
//      QK: S^T = K.Q^T (16 MFMA); single-pass softmax in regs; PV: 16 MFMA.
// ---------------------------------------------------------------------------
template<bool TAIL>
__global__ __launch_bounds__(512, 2) void fusedRing(
    const float* __restrict__ x, const float* __restrict__ Wk0,
    const float* __restrict__ Wv0, const int* __restrict__ rings,
    const int* __restrict__ rsz, const ushort* __restrict__ Q0bf,
    ushort* __restrict__ Kbf, ushort* __restrict__ Vbf,
    float* __restrict__ pm, float* __restrict__ pl, float* __restrict__ po,
    float* __restrict__ feats, int r)
{
    __shared__ ushort Kls[512 * 24];   // 24 KB, rows 48B (2-way banks)
    __shared__ ushort Vls[16 * 520];   // 16.3 KB, V^T rows, stride 1040B
    __shared__ ushort Qls[64 * 24];    // 3 KB
    __shared__ float  outc[4 * 128];
    __shared__ int colsC[64], colsF[64];
    __shared__ int ownIdx[64];
    __shared__ int ownCnt;

    const int t = threadIdx.x, wgid = blockIdx.x;
    const int b = wgid >> 6, h = (wgid >> 3) & 7, sp = wgid & 7;
    const int bh = (b << 3) + h;
    const int n  = TAIL ? 0 : rsz[r];
    const int np = (r > 0) ? rsz[r - 1] : 0;
    const int keybase = sp << 9;

    if (t < 64) colsC[t] = (r > 0 && t < np) ? rings[(r-1)*64 + t] : -1;
    else if (t < 128) { int q = t - 64; colsF[q] = (!TAIL && q < n) ? rings[r*64 + q] : -1; }
    if (t == 0) ownCnt = 0;
    __syncthreads();

    // ---------------- 1) stage ----------------
    if (!TAIL) {
        {   // K rows: thread = key
            const uint4* src = (const uint4*)(Kbf + ((bh << 12) + keybase + t) * 16);
            uint4 a0 = src[0], a1 = src[1];
            *(uint4*)&Kls[t*24]     = a0;
            *(uint4*)&Kls[t*24 + 8] = a1;
        }
        {   // V^T rows: d = t>>5, 16-key chunk = t&31
            int d = t >> 5, c32 = t & 31;
            const uint4* src = (const uint4*)(Vbf + (((bh << 4) + d) << 12) + keybase + (c32 << 4));
            uint4 a0 = src[0], a1 = src[1];
            *(uint4*)&Vls[d*520 + (c32 << 4)]     = a0;
            *(uint4*)&Vls[d*520 + (c32 << 4) + 8] = a1;
        }
        if (t < 128) {  // Q rows (ring-r cols), zero-pad beyond n
            int q = t >> 1, half = t & 1;
            int cq = colsF[q];
            uint4 qv = make_uint4(0u, 0u, 0u, 0u);
            if (cq >= 0)
                qv = *(const uint4*)(Q0bf + ((bh << 12) + cq) * 16 + half * 8);
            *(uint4*)&Qls[q*24 + half*8] = qv;
        }
    }
    __syncthreads();

    // ---------------- 2) combine ring r-1 ----------------
    if (r > 0) {
        const int bufp = (r - 1) & 1;
        if (t < np) {
            int cq = colsC[t];
            if (cq >= keybase && cq < keybase + 512) {
                int slot = atomicAdd(&ownCnt, 1);
                ownIdx[slot] = t;
            }
        }
        __syncthreads();
        const int cnt = ownCnt;
        for (int base = 0; base < cnt; base += 4) {
            {
                int slot = t >> 7, c = t & 127;
                int ow = base + slot;
                if (ow < cnt) {
                    int j = ownIdx[ow];
                    int col = colsC[j];
                    int hh = c >> 4, dd = c & 15;
                    int p0 = ((bufp << 5) + (b << 3) + hh) * 1024 + j;
                    float mstar = -1e30f;
#pragma unroll
                    for (int s2 = 0; s2 < 16; ++s2)
                        mstar = fmaxf(mstar, pm[p0 + (s2 << 6)]);
                    float lstar = 0.f, osum = 0.f;
#pragma unroll
                    for (int s2 = 0; s2 < 16; ++s2) {
                        int pi = p0 + (s2 << 6);
                        float e = __expf(pm[pi] - mstar);
                        lstar += pl[pi] * e;
                        osum  += po[(pi << 4) + dd] * e;
                    }
                    float outv = osum / lstar + x[(((b << 7) + c) << 12) + col];
                    outc[(slot << 7) + c] = outv;
                    if (h == 0) feats[(((b << 7) + c) << 12) + col] = outv;
                }
            }
            __syncthreads();
            if (!TAIL && t < 128) {
                int slot = t >> 5;
                int ow = base + slot;
                if (ow < cnt) {
                    int task = t & 31;
                    int isV = task >> 4, dd = task & 15;
                    int col = colsC[ownIdx[ow]];
                    const float* W = isV ? Wv0 : Wk0;
                    const float* oc = &outc[slot << 7];
                    int row = (h << 4) + dd;
                    float acc = 0.f;
                    for (int c2 = 0; c2 < Cn; ++c2)
                        acc += W[(row << 7) + c2] * oc[c2];
                    ushort bfv = f2bf(acc);
                    if (isV) {
                        Vbf[(((bh << 4) + dd) << 12) + col] = bfv;
                        Vls[dd*520 + (col - keybase)] = bfv;
                    } else {
                        Kbf[((bh << 12) + col) * 16 + dd] = bfv;
                        Kls[(col - keybase)*24 + dd] = bfv;
                    }
                }
            }
            __syncthreads();
        }
    }
    if (TAIL) return;

    // ---------------- 3) MFMA flash ring r ----------------
    const int w = t >> 6, lane = t & 63;
    const int qt = w & 3, kh = w >> 2;
    const int buf = r & 1;
    if (qt * 16 < n) {
        const int lm = lane & 15, lg = lane >> 4;
        bhalf4 qf = *(const bhalf4*)&Qls[(qt*16 + lm)*24 + (lg << 2)];
        const int key0 = kh << 8;
        f32x4 sc[16];
#pragma unroll
        for (int kt = 0; kt < 16; ++kt) {
            bhalf4 kf = *(const bhalf4*)&Kls[(key0 + (kt << 4) + lm)*24 + (lg << 2)];
            f32x4 z = {0.f, 0.f, 0.f, 0.f};
            sc[kt] = __builtin_amdgcn_mfma_f32_16x16x16bf16_1k(kf, qf, z, 0, 0, 0);
        }
        float m = -1e30f;
#pragma unroll
        for (int kt = 0; kt < 16; ++kt) {
            m = fmaxf(m, fmaxf(fmaxf(sc[kt][0], sc[kt][1]), fmaxf(sc[kt][2], sc[kt][3])));
        }
        m = fmaxf(m, __shfl_xor(m, 16));
        m = fmaxf(m, __shfl_xor(m, 32));
        float lsum = 0.f;
        bhalf4 pf[16];
#pragma unroll
        for (int kt = 0; kt < 16; ++kt) {
            float p0 = __expf((sc[kt][0] - m) * 0.25f);
            float p1 = __expf((sc[kt][1] - m) * 0.25f);
            float p2 = __expf((sc[kt][2] - m) * 0.25f);
            float p3 = __expf((sc[kt][3] - m) * 0.25f);
            lsum += (p0 + p1) + (p2 + p3);
            bhalf4 pv;
            pv[0] = (short)f2bf(p0); pv[1] = (short)f2bf(p1);
            pv[2] = (short)f2bf(p2); pv[3] = (short)f2bf(p3);
            pf[kt] = pv;
        }
        lsum += __shfl_xor(lsum, 16);
        lsum += __shfl_xor(lsum, 32);
        f32x4 oacc = {0.f, 0.f, 0.f, 0.f};
#pragma unroll
        for (int kt = 0; kt < 16; ++kt) {
            bhalf4 vf = *(const bhalf4*)&Vls[lm*520 + key0 + (kt << 4) + (lg << 2)];
            oacc = __builtin_amdgcn_mfma_f32_16x16x16bf16_1k(pf[kt], vf, oacc, 0, 0, 0);
        }
        const int pb = ((((buf << 5) + bh) << 4) | ((sp << 1) + kh)) * 64;
        if (lg == 0) {
            pm[pb + qt*16 + lm] = m * 0.25f;   // scaled: combine merges with exp(pm-mstar)
            pl[pb + qt*16 + lm] = lsum;
        }
#pragma unroll
        for (int reg = 0; reg < 4; ++reg)
            po[(pb + qt*16 + (lg << 2) + reg) * 16 + lm] = oacc[reg];
    }
}

// ---------------------------------------------------------------------------
// Epilogue 1: Va = Wv0@anchor_feats, Kn = head-normalize(Wk1@anchor_feats)
// ---------------------------------------------------------------------------
__global__ __launch_bounds__(128) void epi1(
    const float* __restrict__ feats, const float* __restrict__ Wv0,
    const float* __restrict__ Wk1, const int* __restrict__ rings,
    float* __restrict__ Va, float* __restrict__ Kn)
{
    int b = blockIdx.x;
    int i = threadIdx.x;
    int anchor = rings[0];
    __shared__ float la[128];
    __shared__ float kk2[128];
    la[i] = feats[((b * Cn + i) << 12) + anchor];
    __syncthreads();
    float va = 0.f, k1 = 0.f;
    for (int c = 0; c < 128; ++c) {
        va += Wv0[i * 128 + c] * la[c];
        k1 += Wk1[i * 128 + c] * la[c];
    }
    Va[b * 128 + i] = va;
    kk2[i] = k1 * k1;
    __syncthreads();
    float ss = 0.f;
    int hb = i & ~15;
    for (int d = 0; d < 16; ++d) ss += kk2[hb + d];
    Kn[b * 128 + i] = k1 * rsqrtf(ss + 1e-8f);
}

// ---------------------------------------------------------------------------
// Epilogue 2: reg-tiled. Block = 32 cols, 256 thr; W^T staged in LDS once.
// thread (og=t&31 -> 4 outputs, colg=t>>5 -> 4 cols), 4x4 FMA tile.
// ---------------------------------------------------------------------------
__global__ __launch_bounds__(256) void epi2(
    const float* __restrict__ x, const float* __restrict__ Wq1,
    const float* __restrict__ Va, const float* __restrict__ Kn,
    float* __restrict__ scores)
{
    __shared__ float Wt[128 * 132];
    __shared__ float lxT[128 * 36];
    const int bid = blockIdx.x, t = threadIdx.x;
    const int b = bid >> 7, col0 = (bid & 127) << 5;
    for (int idx = t; idx < 128 * 128; idx += 256) {
        int o = idx >> 7, c = idx & 127;
        Wt[c*132 + o] = Wq1[idx];
    }
    for (int idx = t; idx < 128 * 32; idx += 256) {
        int c = idx >> 5, col = idx & 31;
        lxT[c*36 + col] = x[(((b << 7) + c) << 12) + col0 + col] + Va[(b << 7) + c];
    }
    __syncthreads();
    const int og = t & 31, colg = t >> 5;
    const int o0 = og << 2, cl0 = colg << 2;
    float acc[4][4];
#pragma unroll
    for (int i = 0; i < 4; ++i)
#pragma unroll
        for (int j = 0; j < 4; ++j) acc[i][j] = 0.f;
    for (int c = 0; c < 128; ++c) {
        f32x4 wv = *(const f32x4*)&Wt[c*132 + o0];
        f32x4 xv = *(const f32x4*)&lxT[c*36 + cl0];
#pragma unroll
        for (int i = 0; i < 4; ++i)
#pragma unroll
            for (int j = 0; j < 4; ++j) acc[i][j] += wv[i] * xv[j];
    }
    float kn4[4];
#pragma unroll
    for (int i = 0; i < 4; ++i) kn4[i] = Kn[(b << 7) + o0 + i];
    float res[4];
#pragma unroll
    for (int j = 0; j < 4; ++j) {
        float ss = acc[0][j]*acc[0][j] + acc[1][j]*acc[1][j]
                 + acc[2][j]*acc[2][j] + acc[3][j]*acc[3][j];
        ss += __shfl_xor(ss, 1);
        ss += __shfl_xor(ss, 2);
        float rs = rsqrtf(ss + 1e-8f);
        float mp = (acc[0][j]*kn4[0] + acc[1][j]*kn4[1]
                  + acc[2][j]*kn4[2] + acc[3][j]*kn4[3]) * rs;
#pragma unroll
        for (int msk = 1; msk <= 16; msk <<= 1) mp += __shfl_xor(mp, msk);
        res[j] = 0.5f + mp * (1.0f / 16.0f);
    }
    if (og == 0) {
#pragma unroll
        for (int j = 0; j < 4; ++j)
            scores[(b << 12) + col0 + cl0 + j] = res[j];
    }
}

// ---------------------------------------------------------------------------
// Launcher: 1 init + 127 fused + 1 tail + 2 epilogues = 131 launches.
// ---------------------------------------------------------------------------
extern "C" void kernel_launch(void* const* d_in, const int* in_sizes, int n_in,
                              void* d_out, int out_size, void* d_ws, size_t ws_size,
                              hipStream_t stream) {
    const float* x   = (const float*)d_in[0];
    const float* Wq0 = (const float*)d_in[1];
    const float* Wk0 = (const float*)d_in[2];
    const float* Wv0 = (const float*)d_in[3];
    const float* Wq1 = (const float*)d_in[4];
    const float* Wk1 = (const float*)d_in[5];
    const int*   rings = (const int*)d_in[6];
    const int*   rsz   = (const int*)d_in[7];

    float* feats  = (float*)d_out;                 // (B,C,F)
    float* scores = feats + Bn * Cn * Fn;          // (B,F)

    float*  ws   = (float*)d_ws;
    ushort* Q0bf = (ushort*)ws;
    ushort* Kbf  = (ushort*)(ws + OFF_K);
    ushort* Vbf  = (ushort*)(ws + OFF_V);
    float*  pm   = ws + OFF_PM;
    float*  pl   = ws + OFF_PL;
    float*  po   = ws + OFF_PO;
    float*  Va   = ws + OFF_VA;
    float*  Kn   = ws + OFF_KN;

    initQKV<<<256, 512, 0, stream>>>(x, Wq0, Wk0, Wv0, Q0bf, Kbf, Vbf);

    for (int r = 0; r < NRINGS; ++r) {
        fusedRing<false><<<256, 512, 0, stream>>>(
            x, Wk0, Wv0, rings, rsz, Q0bf, Kbf, Vbf, pm, pl, po, feats, r);
    }
    fusedRing<true><<<256, 512, 0, stream>>>(
        x, Wk0, Wv0, rings, rsz, Q0bf, Kbf, Vbf, pm, pl, po, feats, NRINGS);

    epi1<<<Bn, 128, 0, stream>>>(feats, Wv0, Wk1, rings, Va, Kn);
    epi2<<<512, 256, 0, stream>>>(x, Wq1, Va, Kn, scores);
}